// Round 3
// baseline (54.663 us; speedup 1.0000x reference)
//
#include <hip/hip_runtime.h>

// GCNAggregator: B=4096 rows, K=32 neighbor indices into U=16384 node tables
// of D=256 f32. Set-semantics mask, symmetric GCN norm:
//   out_feats[b,:]  = sum_{unique u in row b} feat[u,:]  / (sqrt(rowcnt_b)*sqrt(colcnt_u))
//   out_noise[b,:]  = same with noise table
// d_out = [to_feats (B*D) | to_noise (B*D)] f32.
//
// R3: phased U-slicing in the gather. Per-XCD working set (~20 MB) >> 4 MB L2,
// so the un-phased gather pulls ~256 MiB from L3. Processing u in 8 slices of
// 2048 keeps the per-phase footprint (~2.6 MB) L2-resident per XCD; repeat
// references within a phase become L2 hits. Phase test is wave-uniform
// (broadcast u lives in SGPR) -> s_cbranch, no divergence.

#define B_ 4096
#define K_ 32
#define U_ 16384
#define D_ 256
#define NPHASE 8
#define PHASE_SHIFT 11   // log2(U_/NPHASE) = log2(2048)

// Pass 0: zero colcnt (own kernel; rocclr fill was 43 us for 64 KB).
__global__ __launch_bounds__(256) void gcn_zero(int* __restrict__ colcnt) {
    colcnt[blockIdx.x * 256 + threadIdx.x] = 0;
}

// Pass 1: per-row dedup (wave-local, lanes 0..31 hold the 32 indices),
// atomicAdd unique (b,u) into colcnt[u].
__global__ __launch_bounds__(256) void gcn_colcount(const int* __restrict__ idx,
                                                    int* __restrict__ colcnt) {
    const int wave = (blockIdx.x * blockDim.x + threadIdx.x) >> 6;
    const int lane = threadIdx.x & 63;
    if (wave >= B_) return;

    const int kk = lane & 31;                  // lanes 32..63 mirror 0..31
    const int u = idx[wave * K_ + kk];

    bool dup = false;
    #pragma unroll
    for (int j = 0; j < K_; ++j) {
        const int uj = __shfl(u, j);
        if (j < kk && uj == u) dup = true;     // first occurrence wins
    }
    if (lane < 32 && !dup) atomicAdd(&colcnt[u], 1);
}

// Pass 2: one wave per row, phased over U-slices.
__global__ __launch_bounds__(256) void gcn_gather(const int* __restrict__ idx,
                                                  const float4* __restrict__ feat,
                                                  const float4* __restrict__ noise,
                                                  const int* __restrict__ colcnt,
                                                  float4* __restrict__ out) {
    const int wavesPerBlock = blockDim.x >> 6;
    const int row = blockIdx.x * wavesPerBlock + (threadIdx.x >> 6);
    const int lane = threadIdx.x & 63;
    if (row >= B_) return;

    const int kk = lane & 31;
    const int u = idx[row * K_ + kk];

    bool dup = false;
    #pragma unroll
    for (int j = 0; j < K_; ++j) {
        const int uj = __shfl(u, j);
        if (j < kk && uj == u) dup = true;
    }
    const unsigned long long uniq = __ballot(!dup) & 0xFFFFFFFFull;
    const int rowcnt = __popcll(uniq);

    // weight for slot kk; duplicates contribute 0. colcnt[u] >= 1.
    float w = 0.0f;
    if (!dup) w = rsqrtf((float)(rowcnt * colcnt[u]));

    // Broadcast all 32 (u, w) pairs to SGPRs (loop-invariant readlanes).
    int   us[K_];
    float wk[K_];
    #pragma unroll
    for (int k = 0; k < K_; ++k) {
        us[k] = __builtin_amdgcn_readlane(u, k);
        wk[k] = __uint_as_float(
            (unsigned)__builtin_amdgcn_readlane((int)__float_as_uint(w), k));
    }

    float4 accf = make_float4(0.f, 0.f, 0.f, 0.f);
    float4 accn = make_float4(0.f, 0.f, 0.f, 0.f);

    for (int p = 0; p < NPHASE; ++p) {
        #pragma unroll
        for (int k = 0; k < K_; ++k) {
            if ((us[k] >> PHASE_SHIFT) == p) {   // wave-uniform branch
                const float4 vf = feat[us[k] * (D_ / 4) + lane];
                const float4 vn = noise[us[k] * (D_ / 4) + lane];
                const float wkk = wk[k];
                accf.x = fmaf(wkk, vf.x, accf.x);
                accf.y = fmaf(wkk, vf.y, accf.y);
                accf.z = fmaf(wkk, vf.z, accf.z);
                accf.w = fmaf(wkk, vf.w, accf.w);
                accn.x = fmaf(wkk, vn.x, accn.x);
                accn.y = fmaf(wkk, vn.y, accn.y);
                accn.z = fmaf(wkk, vn.z, accn.z);
                accn.w = fmaf(wkk, vn.w, accn.w);
            }
        }
    }

    out[row * (D_ / 4) + lane] = accf;                 // to_feats
    out[(B_ + row) * (D_ / 4) + lane] = accn;          // to_noise_feats
}

extern "C" void kernel_launch(void* const* d_in, const int* in_sizes, int n_in,
                              void* d_out, int out_size, void* d_ws, size_t ws_size,
                              hipStream_t stream) {
    const int*    idx   = (const int*)d_in[0];        // [B,K] int32
    const float4* feat  = (const float4*)d_in[1];     // [U,D] f32
    const float4* noise = (const float4*)d_in[2];     // [U,D] f32
    float4*       out   = (float4*)d_out;             // [2*B, D] f32
    int*          colcnt = (int*)d_ws;                // U ints

    gcn_zero<<<U_ / 256, 256, 0, stream>>>(colcnt);
    gcn_colcount<<<B_ / 4, 256, 0, stream>>>(idx, colcnt);
    gcn_gather<<<B_ / 4, 256, 0, stream>>>(idx, feat, noise, colcnt, out);
}

// Round 4
// 40.653 us; speedup vs baseline: 1.3446x; 1.3446x over previous
//
#include <hip/hip_runtime.h>

// GCNAggregator: B=4096 rows, K=32 neighbor indices into U=16384 node tables
// of D=256 f32. Set-semantics mask, symmetric GCN norm.
//   out_feats[b,:] = sum_{unique u in row b} feat[u,:] / (sqrt(rowcnt_b)*sqrt(colcnt_u))
// d_out = [to_feats (B*D) | to_noise (B*D)] f32.
//
// R4: bytes-bound hypothesis. Gather ran at ~6 TB/s effective on 256 MiB of
// f32 reads — same rate the 256 MiB harness fills achieve, i.e. we're at the
// machine's streaming ceiling. So: halve the bytes. Per call, convert both
// tables into one packed bf16 table [U][1 KiB] = {feat 512B | noise 512B} in
// ws; gather then needs ONE dwordx4 per lane per k (lanes 0..31 = feat dims,
// lanes 32..63 = noise dims). Gather traffic 256 -> 128 MiB.
// bf16 RNE error ~0.004 extra vs 0.0355 threshold.

#define B_ 4096
#define K_ 32
#define U_ 16384
#define D_ 256
#define NPHASE 8
#define PHASE_SHIFT 11   // log2(U_/NPHASE)

__device__ __forceinline__ unsigned bf16_rne(float x) {
    const unsigned u = __float_as_uint(x);
    return (u + 0x7FFFu + ((u >> 16) & 1u)) >> 16;
}
__device__ __forceinline__ unsigned pack2(float lo, float hi) {
    return bf16_rne(lo) | (bf16_rne(hi) << 16);
}
__device__ __forceinline__ float blo(unsigned v) { return __uint_as_float(v << 16); }
__device__ __forceinline__ float bhi(unsigned v) { return __uint_as_float(v & 0xFFFF0000u); }

// Pass 0: zero colcnt + build packed bf16 table. 1,048,576 threads; each
// converts 8 f32 (two float4 reads) -> 8 bf16 (one uint4 write).
// packed row u = 64 uint4: slots 0..31 feat dims, 32..63 noise dims.
__global__ __launch_bounds__(256) void gcn_prep(const float4* __restrict__ feat,
                                                const float4* __restrict__ noise,
                                                uint4* __restrict__ packed,
                                                int* __restrict__ colcnt) {
    const int gid = blockIdx.x * 256 + threadIdx.x;
    if (gid < U_) colcnt[gid] = 0;

    const int half = U_ * D_ / 8;            // 524288 slots per table
    const bool isNoise = gid >= half;
    const int t = isNoise ? gid - half : gid;
    const int u = t >> 5;                    // 32 slots of 8 dims per u
    const int s = t & 31;

    const float4* src = isNoise ? noise : feat;
    const float4 a = src[u * (D_ / 4) + s * 2];
    const float4 b = src[u * (D_ / 4) + s * 2 + 1];

    uint4 o;
    o.x = pack2(a.x, a.y);
    o.y = pack2(a.z, a.w);
    o.z = pack2(b.x, b.y);
    o.w = pack2(b.z, b.w);
    packed[u * 64 + (isNoise ? 32 : 0) + s] = o;
}

// Pass 1: per-row dedup (wave-local), atomicAdd unique (b,u) into colcnt[u].
__global__ __launch_bounds__(256) void gcn_colcount(const int* __restrict__ idx,
                                                    int* __restrict__ colcnt) {
    const int wave = (blockIdx.x * blockDim.x + threadIdx.x) >> 6;
    const int lane = threadIdx.x & 63;
    if (wave >= B_) return;

    const int kk = lane & 31;
    const int u = idx[wave * K_ + kk];

    bool dup = false;
    #pragma unroll
    for (int j = 0; j < K_; ++j) {
        const int uj = __shfl(u, j);
        if (j < kk && uj == u) dup = true;
    }
    if (lane < 32 && !dup) atomicAdd(&colcnt[u], 1);
}

// Pass 2: one wave per row. Lanes 0..31 accumulate feat dims (8 each),
// lanes 32..63 accumulate noise dims. One dwordx4 gather per k.
__global__ __launch_bounds__(256) void gcn_gather(const int* __restrict__ idx,
                                                  const uint4* __restrict__ packed,
                                                  const int* __restrict__ colcnt,
                                                  float4* __restrict__ out) {
    const int row = blockIdx.x * 4 + (threadIdx.x >> 6);
    const int lane = threadIdx.x & 63;

    const int kk = lane & 31;
    const int u = idx[row * K_ + kk];

    bool dup = false;
    #pragma unroll
    for (int j = 0; j < K_; ++j) {
        const int uj = __shfl(u, j);
        if (j < kk && uj == u) dup = true;
    }
    const int rowcnt = __popcll(__ballot(!dup) & 0xFFFFFFFFull);

    float w = 0.0f;
    if (!dup) w = rsqrtf((float)(rowcnt * colcnt[u]));

    // broadcast all 32 (u,w) to SGPRs (compile-time readlane)
    int   us[K_]; float wk[K_];
    #pragma unroll
    for (int k = 0; k < K_; ++k) {
        us[k] = __builtin_amdgcn_readlane(u, k);
        wk[k] = __uint_as_float(
            (unsigned)__builtin_amdgcn_readlane((int)__float_as_uint(w), k));
    }

    float a0 = 0.f, a1 = 0.f, a2 = 0.f, a3 = 0.f;
    float a4 = 0.f, a5 = 0.f, a6 = 0.f, a7 = 0.f;

    for (int p = 0; p < NPHASE; ++p) {
        #pragma unroll
        for (int k = 0; k < K_; ++k) {
            if ((us[k] >> PHASE_SHIFT) == p) {   // wave-uniform branch
                const uint4 v = packed[us[k] * 64 + lane];
                const float wkk = wk[k];
                a0 = fmaf(wkk, blo(v.x), a0);
                a1 = fmaf(wkk, bhi(v.x), a1);
                a2 = fmaf(wkk, blo(v.y), a2);
                a3 = fmaf(wkk, bhi(v.y), a3);
                a4 = fmaf(wkk, blo(v.z), a4);
                a5 = fmaf(wkk, bhi(v.z), a5);
                a6 = fmaf(wkk, blo(v.w), a6);
                a7 = fmaf(wkk, bhi(v.w), a7);
            }
        }
    }

    // lanes 0..31: to_feats[row][lane*8..+8); lanes 32..63: to_noise same dims
    const int base = (lane < 32) ? (row * (D_ / 4) + lane * 2)
                                 : (B_ * (D_ / 4) + row * (D_ / 4) + (lane - 32) * 2);
    out[base]     = make_float4(a0, a1, a2, a3);
    out[base + 1] = make_float4(a4, a5, a6, a7);
}

extern "C" void kernel_launch(void* const* d_in, const int* in_sizes, int n_in,
                              void* d_out, int out_size, void* d_ws, size_t ws_size,
                              hipStream_t stream) {
    const int*    idx   = (const int*)d_in[0];        // [B,K] int32
    const float4* feat  = (const float4*)d_in[1];     // [U,D] f32
    const float4* noise = (const float4*)d_in[2];     // [U,D] f32
    float4*       out   = (float4*)d_out;             // [2*B, D] f32

    uint4* packed = (uint4*)d_ws;                     // 16 MiB packed bf16 table
    int*   colcnt = (int*)((char*)d_ws + 32u * 1024 * 1024);  // 64 KiB

    gcn_prep<<<(2 * U_ * D_ / 8) / 256, 256, 0, stream>>>(feat, noise, packed, colcnt);
    gcn_colcount<<<B_ / 4, 256, 0, stream>>>(idx, colcnt);
    gcn_gather<<<B_ / 4, 256, 0, stream>>>(idx, packed, colcnt, out);
}

// Round 8
// 40.027 us; speedup vs baseline: 1.3656x; 1.0156x over previous
//
#include <hip/hip_runtime.h>

// GCNAggregator: B=4096 rows, K=32 neighbor indices into U=16384 node tables
// of D=256 f32. Set-semantics mask, symmetric GCN norm.
//   out_feats[b,:] = sum_{unique u in row b} feat[u,:] / (sqrt(rowcnt_b)*sqrt(colcnt_u))
// d_out = [to_feats (B*D) | to_noise (B*D)] f32.
//
// R8 == R7 with the nontemporal-store type fixed (clang ext_vector_type).
// 3-node chain, colcount hidden in N2:
//   N1 prep_feat : zero colcnt + convert feat->bf16 half   (24 MiB)
//   N2 prep_noise: convert noise->bf16 half + colcount     (24.5 MiB)
//   N3 gather    : one dwordx4/lane/k from packed table    (128 MiB + 8 MiB out)
// Packed table [U][1 KiB] = {feat 512B | noise 512B} bf16, nontemporal stores.

#define B_ 4096
#define K_ 32
#define U_ 16384
#define D_ 256
#define HALF_SLOTS (U_ * D_ / 8)       // 524288 uint4 slots per table

typedef unsigned int uint4n __attribute__((ext_vector_type(4)));

__device__ __forceinline__ unsigned bf16_rne(float x) {
    const unsigned u = __float_as_uint(x);
    return (u + 0x7FFFu + ((u >> 16) & 1u)) >> 16;
}
__device__ __forceinline__ unsigned pack2(float lo, float hi) {
    return bf16_rne(lo) | (bf16_rne(hi) << 16);
}
__device__ __forceinline__ float blo(unsigned v) { return __uint_as_float(v << 16); }
__device__ __forceinline__ float bhi(unsigned v) { return __uint_as_float(v & 0xFFFF0000u); }

// convert one 8-dim slot of a table into the packed row layout:
// packed row u = 64 uint4: slots 0..31 feat dims, 32..63 noise dims.
__device__ __forceinline__ void conv_slot(const float4* __restrict__ src,
                                          uint4n* __restrict__ packed,
                                          int t, int half_off) {
    const int u = t >> 5;                    // 32 slots of 8 dims per u
    const int s = t & 31;
    const float4 a = src[u * (D_ / 4) + s * 2];
    const float4 b = src[u * (D_ / 4) + s * 2 + 1];
    uint4n o;
    o.x = pack2(a.x, a.y);
    o.y = pack2(a.z, a.w);
    o.z = pack2(b.x, b.y);
    o.w = pack2(b.z, b.w);
    __builtin_nontemporal_store(o, &packed[u * 64 + half_off + s]);
}

// N1: zero colcnt + convert feat half. 2048 blocks x 256 thr.
__global__ __launch_bounds__(256) void gcn_prep_feat(const float4* __restrict__ feat,
                                                     uint4n* __restrict__ packed,
                                                     int* __restrict__ colcnt) {
    const int gid = blockIdx.x * 256 + threadIdx.x;
    if (gid < U_) colcnt[gid] = 0;
    conv_slot(feat, packed, gid, 0);
}

// N2: convert noise half + colcount (first 4096 waves each count 1 row).
__global__ __launch_bounds__(256) void gcn_prep_noise(const int* __restrict__ idx,
                                                      const float4* __restrict__ noise,
                                                      uint4n* __restrict__ packed,
                                                      int* __restrict__ colcnt) {
    const int gid = blockIdx.x * 256 + threadIdx.x;
    conv_slot(noise, packed, gid, 32);

    const int wg = gid >> 6;                 // global wave id, 0..8191
    if (wg < B_) {
        const int lane = threadIdx.x & 63;
        const int kk = lane & 31;            // lanes 32..63 mirror 0..31
        const int u = idx[wg * K_ + kk];
        bool dup = false;
        #pragma unroll
        for (int j = 0; j < K_; ++j) {
            const int uj = __shfl(u, j);
            if (j < kk && uj == u) dup = true;   // first occurrence wins
        }
        if (lane < 32 && !dup) atomicAdd(&colcnt[u], 1);
    }
}

// N3: gather. One wave per row; lanes 0..31 feat dims, 32..63 noise dims.
__global__ __launch_bounds__(256) void gcn_gather(const int* __restrict__ idx,
                                                  const uint4n* __restrict__ packed,
                                                  const int* __restrict__ colcnt,
                                                  float4* __restrict__ out) {
    const int row = blockIdx.x * 4 + (threadIdx.x >> 6);
    const int lane = threadIdx.x & 63;

    const int kk = lane & 31;
    const int u = idx[row * K_ + kk];

    bool dup = false;
    #pragma unroll
    for (int j = 0; j < K_; ++j) {
        const int uj = __shfl(u, j);
        if (j < kk && uj == u) dup = true;
    }
    const int rowcnt = __popcll(__ballot(!dup) & 0xFFFFFFFFull);

    float w = 0.0f;
    if (!dup) w = rsqrtf((float)(rowcnt * colcnt[u]));

    // broadcast all 32 (u,w) to SGPRs (compile-time readlane)
    int us[K_]; float wk[K_];
    #pragma unroll
    for (int k = 0; k < K_; ++k) {
        us[k] = __builtin_amdgcn_readlane(u, k);
        wk[k] = __uint_as_float(
            (unsigned)__builtin_amdgcn_readlane((int)__float_as_uint(w), k));
    }

    float a0 = 0.f, a1 = 0.f, a2 = 0.f, a3 = 0.f;
    float a4 = 0.f, a5 = 0.f, a6 = 0.f, a7 = 0.f;

    #pragma unroll
    for (int k = 0; k < K_; ++k) {
        const uint4n v = packed[us[k] * 64 + lane];
        const float wkk = wk[k];
        a0 = fmaf(wkk, blo(v.x), a0);
        a1 = fmaf(wkk, bhi(v.x), a1);
        a2 = fmaf(wkk, blo(v.y), a2);
        a3 = fmaf(wkk, bhi(v.y), a3);
        a4 = fmaf(wkk, blo(v.z), a4);
        a5 = fmaf(wkk, bhi(v.z), a5);
        a6 = fmaf(wkk, blo(v.w), a6);
        a7 = fmaf(wkk, bhi(v.w), a7);
    }

    // lanes 0..31: to_feats[row][lane*8..+8); lanes 32..63: to_noise same dims
    const int base = (lane < 32)
        ? (row * (D_ / 4) + lane * 2)
        : (B_ * (D_ / 4) + row * (D_ / 4) + (lane - 32) * 2);
    out[base]     = make_float4(a0, a1, a2, a3);
    out[base + 1] = make_float4(a4, a5, a6, a7);
}

extern "C" void kernel_launch(void* const* d_in, const int* in_sizes, int n_in,
                              void* d_out, int out_size, void* d_ws, size_t ws_size,
                              hipStream_t stream) {
    const int*    idx   = (const int*)d_in[0];        // [B,K] int32
    const float4* feat  = (const float4*)d_in[1];     // [U,D] f32
    const float4* noise = (const float4*)d_in[2];     // [U,D] f32
    float4*       out   = (float4*)d_out;             // [2*B, D] f32

    uint4n* packed = (uint4n*)d_ws;                   // 16 MiB packed bf16 table
    int*    colcnt = (int*)((char*)d_ws + 32u * 1024 * 1024);  // 64 KiB

    gcn_prep_feat <<<HALF_SLOTS / 256, 256, 0, stream>>>(feat, packed, colcnt);
    gcn_prep_noise<<<HALF_SLOTS / 256, 256, 0, stream>>>(idx, noise, packed, colcnt);
    gcn_gather    <<<B_ / 4,          256, 0, stream>>>(idx, packed, colcnt, out);
}